// Round 1
// baseline (36530.060 us; speedup 1.0000x reference)
//
#include <hip/hip_runtime.h>

// Problem constants (from reference)
#define N_TOTAL 150000   // N_USERS + M_ITEMS
#define DIM 64

// SpMM scatter: y[rows[k]] += val[k] * x[cols[k]]  (atomic f32)
// 16 lanes per edge, each lane owns a float4 (4 consecutive d).
__global__ void spmm_atomic_kernel(const int* __restrict__ idx,
                                   const float* __restrict__ val,
                                   const float* __restrict__ x,
                                   float* __restrict__ y,
                                   int nnz) {
    long long t = (long long)blockIdx.x * blockDim.x + threadIdx.x;
    int edge = (int)(t >> 4);
    int lane = (int)(t & 15);
    if (edge >= nnz) return;
    int row = idx[edge];          // idx[0][edge]
    int col = idx[nnz + edge];    // idx[1][edge]
    float v = val[edge];
    const float4 xv = *reinterpret_cast<const float4*>(x + (size_t)col * DIM + lane * 4);
    float* yp = y + (size_t)row * DIM + lane * 4;
    unsafeAtomicAdd(yp + 0, v * xv.x);
    unsafeAtomicAdd(yp + 1, v * xv.y);
    unsafeAtomicAdd(yp + 2, v * xv.z);
    unsafeAtomicAdd(yp + 3, v * xv.w);
}

// out += (w[f] * 0.25) * x   (float4 grid-stride-free direct map)
__global__ void axpy_kernel(const float* __restrict__ x, float* __restrict__ y,
                            const float* __restrict__ w, int f, int n4) {
    int i = blockIdx.x * blockDim.x + threadIdx.x;
    if (i >= n4) return;
    float c = w[f] * 0.25f;
    float4 xv = reinterpret_cast<const float4*>(x)[i];
    float4 yv = reinterpret_cast<float4*>(y)[i];
    yv.x += c * xv.x;
    yv.y += c * xv.y;
    yv.z += c * xv.z;
    yv.w += c * xv.w;
    reinterpret_cast<float4*>(y)[i] = yv;
}

extern "C" void kernel_launch(void* const* d_in, const int* in_sizes, int n_in,
                              void* d_out, int out_size, void* d_ws, size_t ws_size,
                              hipStream_t stream) {
    const float* emb[3]  = {(const float*)d_in[0], (const float*)d_in[1], (const float*)d_in[2]};
    const int*   gidx[3] = {(const int*)d_in[3],   (const int*)d_in[5],   (const int*)d_in[7]};
    const float* gval[3] = {(const float*)d_in[4], (const float*)d_in[6], (const float*)d_in[8]};
    const float* w = (const float*)d_in[9];
    float* out = (float*)d_out;

    const size_t bufElems = (size_t)N_TOTAL * DIM;   // 9.6M floats = 38.4 MB
    float* bufA = (float*)d_ws;
    float* bufB = bufA + bufElems;

    const int nnz = in_sizes[4];  // g_im_val element count

    // Zero the output accumulator (poisoned by harness).
    hipMemsetAsync(out, 0, bufElems * sizeof(float), stream);

    const int n4 = (int)(bufElems / 4);
    dim3 axpyGrid((n4 + 255) / 256);
    long long spmmThreads = (long long)nnz * 16;
    dim3 spmmGrid((unsigned)((spmmThreads + 255) / 256));

    for (int f = 0; f < 3; ++f) {
        // layer-0 embedding contributes directly
        axpy_kernel<<<axpyGrid, 256, 0, stream>>>(emb[f], out, w, f, n4);

        const float* cur = emb[f];
        float* nxt = bufA;
        for (int l = 0; l < 3; ++l) {
            hipMemsetAsync(nxt, 0, bufElems * sizeof(float), stream);
            spmm_atomic_kernel<<<spmmGrid, 256, 0, stream>>>(gidx[f], gval[f], cur, nxt, nnz);
            axpy_kernel<<<axpyGrid, 256, 0, stream>>>(nxt, out, w, f, n4);
            cur = nxt;
            nxt = (nxt == bufA) ? bufB : bufA;
        }
    }
}

// Round 2
// 4004.325 us; speedup vs baseline: 9.1226x; 9.1226x over previous
//
#include <hip/hip_runtime.h>

#define N_TOTAL 150000   // N_USERS + M_ITEMS
#define DIM 64

// ---- CSR build ----

__global__ void hist_kernel(const int* __restrict__ rows, int* __restrict__ cnt, int nnz) {
    int t = blockIdx.x * blockDim.x + threadIdx.x;
    if (t < nnz) atomicAdd(&cnt[rows[t]], 1);
}

// Single-workgroup exclusive scan over n ints (n ~ 150K: ~147 chunks of 1024).
__global__ void scan_kernel(const int* __restrict__ cnt, int* __restrict__ start, int n) {
    __shared__ int sh[1024];
    int carry = 0;
    for (int base = 0; base < n; base += 1024) {
        int i = base + (int)threadIdx.x;
        int v = (i < n) ? cnt[i] : 0;
        sh[threadIdx.x] = v;
        __syncthreads();
        for (int off = 1; off < 1024; off <<= 1) {
            int t = (threadIdx.x >= (unsigned)off) ? sh[threadIdx.x - off] : 0;
            __syncthreads();
            sh[threadIdx.x] += t;
            __syncthreads();
        }
        int incl = sh[threadIdx.x];
        int tot  = sh[1023];
        __syncthreads();           // everyone read sh before next chunk overwrites
        if (i < n) start[i] = carry + incl - v;   // exclusive
        carry += tot;
    }
}

__global__ void scatter_kernel(const int* __restrict__ idx, const float* __restrict__ val,
                               int* __restrict__ cur, int* __restrict__ cs_col,
                               float* __restrict__ cs_val, int nnz) {
    int t = blockIdx.x * blockDim.x + threadIdx.x;
    if (t >= nnz) return;
    int row = idx[t];
    int pos = atomicAdd(&cur[row], 1);
    cs_col[pos] = idx[nnz + t];
    cs_val[pos] = val[t];
}

// ---- out = sum_f (w[f]/4) * emb_f  (layer-0 contribution of all 3 factors) ----
__global__ void init_out_kernel(const float* __restrict__ e0, const float* __restrict__ e1,
                                const float* __restrict__ e2, const float* __restrict__ w,
                                float* __restrict__ out, int n4) {
    int i = blockIdx.x * blockDim.x + threadIdx.x;
    if (i >= n4) return;
    float c0 = w[0] * 0.25f, c1 = w[1] * 0.25f, c2 = w[2] * 0.25f;
    float4 a = reinterpret_cast<const float4*>(e0)[i];
    float4 b = reinterpret_cast<const float4*>(e1)[i];
    float4 c = reinterpret_cast<const float4*>(e2)[i];
    float4 o;
    o.x = c0 * a.x + c1 * b.x + c2 * c.x;
    o.y = c0 * a.y + c1 * b.y + c2 * c.y;
    o.z = c0 * a.z + c1 * b.z + c2 * c.z;
    o.w = c0 * a.w + c1 * b.w + c2 * c.w;
    reinterpret_cast<float4*>(out)[i] = o;
}

// ---- pull SpMM: one 64-lane wave per row; lane d owns dim d.
//      y[row] = sum_k val[k] * x[col[k]] ; out[row] += (w[f]/4) * y[row] ----
__global__ void spmm_csr_kernel(const int* __restrict__ start, const int* __restrict__ cnt,
                                const int* __restrict__ cs_col, const float* __restrict__ cs_val,
                                const float* __restrict__ x, float* __restrict__ y,
                                float* __restrict__ out, const float* __restrict__ w, int f,
                                int nrows) {
    int gid = blockIdx.x * blockDim.x + threadIdx.x;
    int row = gid >> 6;
    int lane = gid & 63;
    if (row >= nrows) return;
    int s = start[row];
    int c = cnt[row];
    float acc = 0.f;
    #pragma unroll 4
    for (int k = s; k < s + c; ++k) {
        acc += cs_val[k] * x[((size_t)cs_col[k] << 6) + lane];
    }
    size_t o = ((size_t)row << 6) + lane;
    y[o] = acc;
    out[o] += w[f] * 0.25f * acc;
}

extern "C" void kernel_launch(void* const* d_in, const int* in_sizes, int n_in,
                              void* d_out, int out_size, void* d_ws, size_t ws_size,
                              hipStream_t stream) {
    const float* emb[3]  = {(const float*)d_in[0], (const float*)d_in[1], (const float*)d_in[2]};
    const int*   gidx[3] = {(const int*)d_in[3],   (const int*)d_in[5],   (const int*)d_in[7]};
    const float* gval[3] = {(const float*)d_in[4], (const float*)d_in[6], (const float*)d_in[8]};
    const float* w = (const float*)d_in[9];
    float* out = (float*)d_out;

    const int nnz = in_sizes[4];
    const size_t bufElems = (size_t)N_TOTAL * DIM;   // 9.6M floats

    // ws layout
    float* bufA   = (float*)d_ws;                    // 38.4 MB
    float* bufB   = bufA + bufElems;                 // 38.4 MB
    float* cs_val = bufB + bufElems;                 // 19.2 MB
    int*   cs_col = (int*)(cs_val + nnz);            // 19.2 MB
    int*   cnt    = cs_col + nnz;                    // 600 KB
    int*   rstart = cnt + N_TOTAL;                   // 600 KB
    int*   rcur   = rstart + N_TOTAL;                // 600 KB

    const int n4 = (int)(bufElems / 4);
    dim3 eltGrid((n4 + 255) / 256);
    dim3 edgeGrid((nnz + 255) / 256);
    dim3 rowGrid((unsigned)(((size_t)N_TOTAL * 64 + 255) / 256));

    // layer-0 contributions of all factors in one pass
    init_out_kernel<<<eltGrid, 256, 0, stream>>>(emb[0], emb[1], emb[2], w, out, n4);

    for (int f = 0; f < 3; ++f) {
        // --- build CSR for this factor's graph ---
        hipMemsetAsync(cnt, 0, N_TOTAL * sizeof(int), stream);
        hist_kernel<<<edgeGrid, 256, 0, stream>>>(gidx[f], cnt, nnz);
        scan_kernel<<<1, 1024, 0, stream>>>(cnt, rstart, N_TOTAL);
        hipMemcpyAsync(rcur, rstart, N_TOTAL * sizeof(int), hipMemcpyDeviceToDevice, stream);
        scatter_kernel<<<edgeGrid, 256, 0, stream>>>(gidx[f], gval[f], rcur, cs_col, cs_val, nnz);

        // --- 3 propagation layers, axpy fused into SpMM epilogue ---
        const float* cur = emb[f];
        float* nxt = bufA;
        for (int l = 0; l < 3; ++l) {
            spmm_csr_kernel<<<rowGrid, 256, 0, stream>>>(rstart, cnt, cs_col, cs_val,
                                                         cur, nxt, out, w, f, N_TOTAL);
            cur = nxt;
            nxt = (nxt == bufA) ? bufB : bufA;
        }
    }
}

// Round 3
// 3142.098 us; speedup vs baseline: 11.6260x; 1.2744x over previous
//
#include <hip/hip_runtime.h>

#define N_TOTAL 150000   // N_USERS + M_ITEMS
#define DIM 64

// ---- CSR build ----

__global__ void hist_kernel(const int* __restrict__ rows, int* __restrict__ cnt, int nnz) {
    int t = blockIdx.x * blockDim.x + threadIdx.x;
    if (t < nnz) atomicAdd(&cnt[rows[t]], 1);
}

// Hierarchical exclusive scan, step 1: per-block (1024 elems, 256 thr x 4).
__global__ void scan_block_kernel(const int* __restrict__ cnt, int* __restrict__ excl,
                                  int* __restrict__ bsum, int n) {
    __shared__ int sh[256];
    int t = threadIdx.x;
    int i0 = blockIdx.x * 1024 + t * 4;
    int v0 = (i0 + 0 < n) ? cnt[i0 + 0] : 0;
    int v1 = (i0 + 1 < n) ? cnt[i0 + 1] : 0;
    int v2 = (i0 + 2 < n) ? cnt[i0 + 2] : 0;
    int v3 = (i0 + 3 < n) ? cnt[i0 + 3] : 0;
    int s = v0 + v1 + v2 + v3;
    sh[t] = s;
    __syncthreads();
    for (int off = 1; off < 256; off <<= 1) {
        int x = (t >= off) ? sh[t - off] : 0;
        __syncthreads();
        sh[t] += x;
        __syncthreads();
    }
    int myexcl = sh[t] - s;
    if (t == 255) bsum[blockIdx.x] = sh[255];
    if (i0 + 0 < n) excl[i0 + 0] = myexcl;
    if (i0 + 1 < n) excl[i0 + 1] = myexcl + v0;
    if (i0 + 2 < n) excl[i0 + 2] = myexcl + v0 + v1;
    if (i0 + 3 < n) excl[i0 + 3] = myexcl + v0 + v1 + v2;
}

// step 2: exclusive scan of block sums (nb <= 256) in place.
__global__ void scan_tops_kernel(int* __restrict__ bsum, int nb) {
    __shared__ int sh[256];
    int t = threadIdx.x;
    int v = (t < nb) ? bsum[t] : 0;
    sh[t] = v;
    __syncthreads();
    for (int off = 1; off < 256; off <<= 1) {
        int x = (t >= off) ? sh[t - off] : 0;
        __syncthreads();
        sh[t] += x;
        __syncthreads();
    }
    if (t < nb) bsum[t] = sh[t] - v;
}

// step 3: add block offsets.
__global__ void scan_add_kernel(int* __restrict__ excl, const int* __restrict__ bsum, int n) {
    int i = blockIdx.x * blockDim.x + threadIdx.x;
    if (i < n) excl[i] += bsum[i >> 10];
}

// Scatter edges into row-grouped order; PACKED (col,val) -> one 8B line touch
// per edge. atomicAdd on rstart turns it into row END; spmm recovers start.
__global__ void scatter_kernel(const int* __restrict__ idx, const float* __restrict__ val,
                               int* __restrict__ rstart, float2* __restrict__ cs, int nnz) {
    int t = blockIdx.x * blockDim.x + threadIdx.x;
    if (t >= nnz) return;
    int row = idx[t];
    int pos = atomicAdd(&rstart[row], 1);
    float2 e;
    e.x = __int_as_float(idx[nnz + t]);
    e.y = val[t];
    cs[pos] = e;
}

// ---- out = sum_f (w[f]/4) * emb_f  (layer-0 contribution of all 3 factors) ----
__global__ void init_out_kernel(const float* __restrict__ e0, const float* __restrict__ e1,
                                const float* __restrict__ e2, const float* __restrict__ w,
                                float* __restrict__ out, int n4) {
    int i = blockIdx.x * blockDim.x + threadIdx.x;
    if (i >= n4) return;
    float c0 = w[0] * 0.25f, c1 = w[1] * 0.25f, c2 = w[2] * 0.25f;
    float4 a = reinterpret_cast<const float4*>(e0)[i];
    float4 b = reinterpret_cast<const float4*>(e1)[i];
    float4 c = reinterpret_cast<const float4*>(e2)[i];
    float4 o;
    o.x = c0 * a.x + c1 * b.x + c2 * c.x;
    o.y = c0 * a.y + c1 * b.y + c2 * c.y;
    o.z = c0 * a.z + c1 * b.z + c2 * c.z;
    o.w = c0 * a.w + c1 * b.w + c2 * c.w;
    reinterpret_cast<float4*>(out)[i] = o;
}

// ---- pull SpMM: one 64-lane wave per row; lane d owns dim d.
//      rend[row] = end (start = end - cnt).  out[row] += (w[f]/4)*y[row] fused.
__global__ void spmm_csr_kernel(const int* __restrict__ rend, const int* __restrict__ cnt,
                                const float2* __restrict__ cs,
                                const float* __restrict__ x, float* __restrict__ y,
                                float* __restrict__ out, const float* __restrict__ w, int f,
                                int nrows) {
    int gid = blockIdx.x * blockDim.x + threadIdx.x;
    int row = gid >> 6;
    int lane = gid & 63;
    if (row >= nrows) return;
    int e = rend[row];
    int c = cnt[row];
    int s = e - c;
    float acc = 0.f;
    #pragma unroll 4
    for (int k = s; k < e; ++k) {
        float2 ed = cs[k];
        acc += ed.y * x[((size_t)__float_as_int(ed.x) << 6) + lane];
    }
    size_t o = ((size_t)row << 6) + lane;
    y[o] = acc;
    out[o] += w[f] * 0.25f * acc;
}

extern "C" void kernel_launch(void* const* d_in, const int* in_sizes, int n_in,
                              void* d_out, int out_size, void* d_ws, size_t ws_size,
                              hipStream_t stream) {
    const float* emb[3]  = {(const float*)d_in[0], (const float*)d_in[1], (const float*)d_in[2]};
    const int*   gidx[3] = {(const int*)d_in[3],   (const int*)d_in[5],   (const int*)d_in[7]};
    const float* gval[3] = {(const float*)d_in[4], (const float*)d_in[6], (const float*)d_in[8]};
    const float* w = (const float*)d_in[9];
    float* out = (float*)d_out;

    const int nnz = in_sizes[4];
    const size_t bufElems = (size_t)N_TOTAL * DIM;   // 9.6M floats

    // ws layout
    float*  bufA   = (float*)d_ws;                   // 38.4 MB
    float*  bufB   = bufA + bufElems;                // 38.4 MB
    float2* cs     = (float2*)(bufB + bufElems);     // 38.4 MB (packed col,val)
    int*    cnt    = (int*)(cs + nnz);               // 600 KB
    int*    rstart = cnt + N_TOTAL;                  // 600 KB
    int*    bsum   = rstart + N_TOTAL;               // 1 KB

    const int n4 = (int)(bufElems / 4);
    const int nScanBlocks = (N_TOTAL + 1023) / 1024;  // 147
    dim3 eltGrid((n4 + 255) / 256);
    dim3 edgeGrid((nnz + 255) / 256);
    dim3 rowGrid((unsigned)(((size_t)N_TOTAL * 64 + 255) / 256));
    dim3 addGrid((N_TOTAL + 255) / 256);

    // layer-0 contributions of all factors in one pass
    init_out_kernel<<<eltGrid, 256, 0, stream>>>(emb[0], emb[1], emb[2], w, out, n4);

    for (int f = 0; f < 3; ++f) {
        // --- build CSR for this factor's graph ---
        hipMemsetAsync(cnt, 0, N_TOTAL * sizeof(int), stream);
        hist_kernel<<<edgeGrid, 256, 0, stream>>>(gidx[f], cnt, nnz);
        scan_block_kernel<<<nScanBlocks, 256, 0, stream>>>(cnt, rstart, bsum, N_TOTAL);
        scan_tops_kernel<<<1, 256, 0, stream>>>(bsum, nScanBlocks);
        scan_add_kernel<<<addGrid, 256, 0, stream>>>(rstart, bsum, N_TOTAL);
        scatter_kernel<<<edgeGrid, 256, 0, stream>>>(gidx[f], gval[f], rstart, cs, nnz);

        // --- 3 propagation layers, axpy fused into SpMM epilogue ---
        const float* cur = emb[f];
        float* nxt = bufA;
        for (int l = 0; l < 3; ++l) {
            spmm_csr_kernel<<<rowGrid, 256, 0, stream>>>(rstart, cnt, cs,
                                                         cur, nxt, out, w, f, N_TOTAL);
            cur = nxt;
            nxt = (nxt == bufA) ? bufB : bufA;
        }
    }
}